// Round 9
// baseline (40839.127 us; speedup 1.0000x reference)
//
#include <hip/hip_runtime.h>

typedef unsigned int u32;
typedef unsigned long long u64;
typedef float f32x4 __attribute__((ext_vector_type(4)));

// np-bit-exact Leaky update: m' = f32(f32(f32(0.95f*m) + cur) - reset)
// reset from PREVIOUS mem; (mem-1>0) === (mem>1) exactly in f32 (Sterbenz).
__device__ __forceinline__ float leaky(float m, float cur) {
  float r = (m > 1.0f) ? 1.0f : 0.0f;
  return __fsub_rn(__fadd_rn(__fmul_rn(0.95f, m), cur), r);
}

// ---------------------------------------------------------------------------
// Phase A: cur1 (exact FMA chain, d ascending) + layer-1 sim; emit per-step
// spike bitmasks to global in [t][kw][sample] layout.  (unchanged — verified)
// ---------------------------------------------------------------------------
__global__ __launch_bounds__(256) void k_spk1(
    const float* __restrict__ x, const float* __restrict__ W1,
    const float* __restrict__ b1, u32* __restrict__ masks,
    int s0, int Sc) {
  __shared__ float w1s[8 * 1024];
  const int tid = threadIdx.x, lane = tid & 63, w = tid >> 6;
  const int sl = blockIdx.x * 4 + w;
  const size_t s = (size_t)s0 + sl;

  float c1[16];
#pragma unroll
  for (int j = 0; j < 16; ++j) c1[j] = 0.0f;
#pragma unroll 1
  for (int ch = 0; ch < 8; ++ch) {
    __syncthreads();
#pragma unroll
    for (int it = 0; it < 8; ++it) {
      int v = tid + it * 256;
      *(f32x4*)(w1s + v * 4) =
          *(const f32x4*)(W1 + (size_t)(ch * 8 + (v >> 8)) * 1024 + (v & 255) * 4);
    }
    __syncthreads();
#pragma unroll 1
    for (int dl = 0; dl < 8; ++dl) {
      float xv = x[s * 64 + ch * 8 + dl];
#pragma unroll
      for (int j = 0; j < 16; ++j)
        c1[j] = fmaf(xv, w1s[dl * 1024 + j * 64 + lane], c1[j]);
    }
  }
#pragma unroll
  for (int j = 0; j < 16; ++j) c1[j] = __fadd_rn(c1[j], b1[j * 64 + lane]);

  float m1[16];
#pragma unroll
  for (int j = 0; j < 16; ++j) m1[j] = 0.0f;

#pragma unroll 1
  for (int t = 0; t < 25; ++t) {
#pragma unroll
    for (int j = 0; j < 16; ++j) {
      m1[j] = leaky(m1[j], c1[j]);
      u64 ball = __ballot(m1[j] > 1.0f);
      if (lane == 0) {
        masks[((size_t)t * 32 + 2 * j) * Sc + sl] = (u32)ball;
        masks[((size_t)t * 32 + 2 * j + 1) * Sc + sl] = (u32)(ball >> 32);
      }
    }
  }
}

// ---------------------------------------------------------------------------
// Phase B: cur2, 16 samples x 1 step per wave. ROUND-9 CHANGE: 4-row
// double-buffered row stream. r8's structure consumed rB only ~300cy after
// its load (marginal vs L2 latency ~200-400cy, W2 never L1-fits, 2 waves/
// SIMD) -> 36% stall. Now each 4-row phase (512 fmaf ~ 1000+cy) covers the
// next 4 rows' loads. VALU-issue side is already at the practical FMA
// ceiling (m07: 66% of 157TF): 1.20ms/dispatch measured vs 1.25ms practical
// floor — this round targets ONLY the stall fraction.
// Arithmetic unchanged (verified r5-r8): k-ascending acc = fmaf(g, w, acc),
// g = wave-uniform (bit ? 1.0f : 0.0f): fma(1,w,c)=RN add = BLAS step,
// fma(0,w,c)=c exactly. Accs/rowbufs = named scalar floats (arch-VGPR form).
// ---------------------------------------------------------------------------
#define FOR16(M) M(0) M(1) M(2) M(3) M(4) M(5) M(6) M(7) \
                 M(8) M(9) M(10) M(11) M(12) M(13) M(14) M(15)
#define FOR16A(M, a, b) M(0,a,b) M(1,a,b) M(2,a,b) M(3,a,b) M(4,a,b) M(5,a,b) \
                        M(6,a,b) M(7,a,b) M(8,a,b) M(9,a,b) M(10,a,b) M(11,a,b) \
                        M(12,a,b) M(13,a,b) M(14,a,b) M(15,a,b)

#define DECL_ACC(i)                                                     \
  float aA##i##_0 = 0.f, aA##i##_1 = 0.f, aA##i##_2 = 0.f, aA##i##_3 = 0.f; \
  float aB##i##_0 = 0.f, aB##i##_1 = 0.f, aB##i##_2 = 0.f, aB##i##_3 = 0.f;

#define LOADW(i) const u32 w##i = (u32)__builtin_amdgcn_readfirstlane((int)mp[i]);

#define DECL_ROWB(p) float p##_0, p##_1, p##_2, p##_3, p##_4, p##_5, p##_6, p##_7;

#define LROWB(p, ROWK) {                                                \
  const f32x4 _q0 = *(const f32x4*)(wp + (size_t)(ROWK) * 512);         \
  const f32x4 _q1 = *(const f32x4*)(wp + (size_t)(ROWK) * 512 + 256);   \
  p##_0 = _q0[0]; p##_1 = _q0[1]; p##_2 = _q0[2]; p##_3 = _q0[3];       \
  p##_4 = _q1[0]; p##_5 = _q1[1]; p##_6 = _q1[2]; p##_7 = _q1[3]; }

#define GS(i, p, MB) { const float g = (w##i & (MB)) ? 1.0f : 0.0f;     \
  aA##i##_0 = fmaf(g, p##_0, aA##i##_0); aA##i##_1 = fmaf(g, p##_1, aA##i##_1); \
  aA##i##_2 = fmaf(g, p##_2, aA##i##_2); aA##i##_3 = fmaf(g, p##_3, aA##i##_3); \
  aB##i##_0 = fmaf(g, p##_4, aB##i##_0); aB##i##_1 = fmaf(g, p##_5, aB##i##_1); \
  aB##i##_2 = fmaf(g, p##_6, aB##i##_2); aB##i##_3 = fmaf(g, p##_7, aB##i##_3); }

#define GROW(p, MB) FOR16A(GS, p, MB)

#define STORE16(i) {                                                    \
  float* op = cur2 + ((size_t)(sl0 + i) * 25 + t) * 512 + lq;           \
  op[0] = __fadd_rn(aA##i##_0, bv0); op[1] = __fadd_rn(aA##i##_1, bv1); \
  op[2] = __fadd_rn(aA##i##_2, bv2); op[3] = __fadd_rn(aA##i##_3, bv3); \
  op[256] = __fadd_rn(aB##i##_0, bv4); op[257] = __fadd_rn(aB##i##_1, bv5); \
  op[258] = __fadd_rn(aB##i##_2, bv6); op[259] = __fadd_rn(aB##i##_3, bv7); }

__global__ __launch_bounds__(256) void k_cur2(
    const float* __restrict__ W2, const float* __restrict__ b2,
    const u32* __restrict__ masks, float* __restrict__ cur2, int Sc) {
  const int tid = threadIdx.x, lane = tid & 63, w = tid >> 6;
  const int task = blockIdx.x * 4 + w;    // grid = (Sc/16)*25/4 blocks
  const int grp = task / 25, t = task - grp * 25;
  const int sl0 = grp * 16;
  const int lq = lane * 4;

  FOR16(DECL_ACC)
  DECL_ROWB(r0) DECL_ROWB(r1) DECL_ROWB(r2) DECL_ROWB(r3)
  DECL_ROWB(r4) DECL_ROWB(r5) DECL_ROWB(r6) DECL_ROWB(r7)

  const float* wp = W2 + lq;              // row k quad0 at wp+k*512, quad1 +256

  // prologue: rows 0..3 into set A
  LROWB(r0, 0) LROWB(r1, 1) LROWB(r2, 2) LROWB(r3, 3)

#pragma unroll 1
  for (int kw = 0; kw < 32; ++kw) {
    const u32* mp = masks + ((size_t)t * 32 + kw) * Sc + sl0;
    FOR16(LOADW)                          // w0..w15 -> SGPRs
    const int kb = kw * 32;
#pragma unroll 1
    for (int k2 = 0; k2 < 32; k2 += 8) {
      const int k = kb + k2;
      // phase A: load rows k+4..k+7 (set B), compute rows k..k+3 (set A)
      LROWB(r4, k + 4) LROWB(r5, k + 5) LROWB(r6, k + 6) LROWB(r7, k + 7)
      { const u32 mb = 1u << k2;   GROW(r0, mb) }      // row k   (k ascending)
      { const u32 mb = 2u << k2;   GROW(r1, mb) }      // row k+1
      { const u32 mb = 4u << k2;   GROW(r2, mb) }      // row k+2
      { const u32 mb = 8u << k2;   GROW(r3, mb) }      // row k+3
      // phase B: load rows k+8..k+11 (set A), compute rows k+4..k+7 (set B)
      const int k8  = (k + 8  < 1024) ? k + 8  : 1023;  // harmless tail clamp
      const int k9  = (k + 9  < 1024) ? k + 9  : 1023;
      const int k10 = (k + 10 < 1024) ? k + 10 : 1023;
      const int k11 = (k + 11 < 1024) ? k + 11 : 1023;
      LROWB(r0, k8) LROWB(r1, k9) LROWB(r2, k10) LROWB(r3, k11)
      { const u32 mb = 16u << k2;  GROW(r4, mb) }      // row k+4
      { const u32 mb = 32u << k2;  GROW(r5, mb) }      // row k+5
      { const u32 mb = 64u << k2;  GROW(r6, mb) }      // row k+6
      { const u32 mb = 128u << k2; GROW(r7, mb) }      // row k+7
    }
  }

  const float bv0 = b2[lq], bv1 = b2[lq + 1], bv2 = b2[lq + 2], bv3 = b2[lq + 3];
  const float bv4 = b2[256 + lq], bv5 = b2[257 + lq];
  const float bv6 = b2[258 + lq], bv7 = b2[259 + lq];
  FOR16(STORE16)
}

// ---------------------------------------------------------------------------
// Phase C: layers 2-3 recurrence off stored cur2 (exact f32 round-trip).
// (unchanged — verified)
// ---------------------------------------------------------------------------
__global__ __launch_bounds__(256) void k_tail(
    const float* __restrict__ cur2, const float* __restrict__ W3,
    const float* __restrict__ b3, float* __restrict__ out, int s0, int Sc) {
  __shared__ float w3s[512];
  const int tid = threadIdx.x, lane = tid & 63, w = tid >> 6;
  const int sl = blockIdx.x * 4 + w;
  for (int i = tid; i < 512; i += 256) w3s[i] = W3[i];
  __syncthreads();

  float m2[8];
#pragma unroll
  for (int j = 0; j < 8; ++j) m2[j] = 0.0f;
  float m3 = 0.0f;
  double s3 = 0.0;
  const float b3v = b3[0];
  const float* cp = cur2 + (size_t)sl * 25 * 512;

#pragma unroll 1
  for (int t = 0; t < 25; ++t) {
    u64 s2b[8];
#pragma unroll
    for (int j = 0; j < 8; ++j) {
      float cur = cp[t * 512 + j * 64 + lane];
      m2[j] = leaky(m2[j], cur);
      s2b[j] = __ballot(m2[j] > 1.0f);
    }
    if (lane == 0) {
      float c3 = 0.0f;
#pragma unroll 1
      for (int j = 0; j < 8; ++j) {
        u64 mm = s2b[j];
        const int nb = j * 64;
        if (mm) {
          int nn = __ffsll(mm) - 1;
          mm &= mm - 1;
          float wv = w3s[nb + nn];
          while (mm) {
            int n2 = __ffsll(mm) - 1;
            mm &= mm - 1;
            float wn = w3s[nb + n2];   // next load issued before dependent add
            c3 = __fadd_rn(c3, wv);
            wv = wn;
          }
          c3 = __fadd_rn(c3, wv);
        }
      }
      c3 = __fadd_rn(c3, b3v);
      m3 = leaky(m3, c3);
      s3 += (double)m3;
    }
  }
  if (lane == 0) {
    double z = s3 / 25.0;
    out[s0 + sl] = (float)(1.0 / (1.0 + exp(-z)));
  }
}

// ---------------------------------------------------------------------------
// Fallback: original verified single-kernel path (used if workspace too small)
// ---------------------------------------------------------------------------
__global__ __launch_bounds__(256) void k_snn(
    const float* __restrict__ x, const float* __restrict__ W1,
    const float* __restrict__ b1, const float* __restrict__ W2,
    const float* __restrict__ b2, const float* __restrict__ W3,
    const float* __restrict__ b3, float* __restrict__ out) {
  __shared__ float w1s[8 * 1024];
  __shared__ float w3s[512];
  __shared__ u32 spkm[4][32];
  const int tid = threadIdx.x, lane = tid & 63, w = tid >> 6;
  const size_t s = (size_t)blockIdx.x * 4 + w;

  for (int i = tid; i < 512; i += 256) w3s[i] = W3[i];

  float c1[16];
#pragma unroll
  for (int j = 0; j < 16; ++j) c1[j] = 0.0f;
#pragma unroll 1
  for (int ch = 0; ch < 8; ++ch) {
    __syncthreads();
#pragma unroll
    for (int it = 0; it < 8; ++it) {
      int v = tid + it * 256;
      *(f32x4*)(w1s + v * 4) =
          *(const f32x4*)(W1 + (size_t)(ch * 8 + (v >> 8)) * 1024 + (v & 255) * 4);
    }
    __syncthreads();
#pragma unroll 1
    for (int dl = 0; dl < 8; ++dl) {
      float xv = x[s * 64 + ch * 8 + dl];
#pragma unroll
      for (int j = 0; j < 16; ++j)
        c1[j] = fmaf(xv, w1s[dl * 1024 + j * 64 + lane], c1[j]);
    }
  }
#pragma unroll
  for (int j = 0; j < 16; ++j) c1[j] = __fadd_rn(c1[j], b1[j * 64 + lane]);

  float m1[16];
#pragma unroll
  for (int j = 0; j < 16; ++j) m1[j] = 0.0f;
  float m2[8];
#pragma unroll
  for (int j = 0; j < 8; ++j) m2[j] = 0.0f;
  float b2l[8];
#pragma unroll
  for (int j = 0; j < 8; ++j) b2l[j] = b2[j * 64 + lane];
  const float b3v = b3[0];
  float m3 = 0.0f;
  double s3 = 0.0;

#pragma unroll 1
  for (int t = 0; t < 25; ++t) {
#pragma unroll
    for (int j = 0; j < 16; ++j) {
      m1[j] = leaky(m1[j], c1[j]);
      u64 ball = __ballot(m1[j] > 1.0f);
      if (lane == 0) {
        spkm[w][2 * j]     = (u32)ball;
        spkm[w][2 * j + 1] = (u32)(ball >> 32);
      }
    }
    __syncthreads();

    float c2[8];
#pragma unroll
    for (int j = 0; j < 8; ++j) c2[j] = 0.0f;
#pragma unroll 1
    for (int kw = 0; kw < 32; ++kw) {
      u32 mask = spkm[w][kw];
      int kbase = kw * 32;
      while (mask) {
        int kk = __ffs(mask) - 1;
        mask &= mask - 1;
        const float* wr = W2 + (size_t)(kbase + kk) * 512;
#pragma unroll
        for (int j = 0; j < 8; ++j)
          c2[j] = __fadd_rn(c2[j], wr[j * 64 + lane]);
      }
    }
    u64 s2b[8];
#pragma unroll
    for (int j = 0; j < 8; ++j) {
      float cur = __fadd_rn(c2[j], b2l[j]);
      m2[j] = leaky(m2[j], cur);
      s2b[j] = __ballot(m2[j] > 1.0f);
    }

    if (lane == 0) {
      float c3 = 0.0f;
#pragma unroll 1
      for (int j = 0; j < 8; ++j) {
        u64 mm = s2b[j];
        int nb = j * 64;
        while (mm) {
          int nn = __ffsll(mm) - 1;
          mm &= mm - 1;
          c3 = __fadd_rn(c3, w3s[nb + nn]);
        }
      }
      c3 = __fadd_rn(c3, b3v);
      m3 = leaky(m3, c3);
      s3 += (double)m3;
    }
    __syncthreads();
  }

  if (lane == 0) {
    double z = s3 / 25.0;
    out[s] = (float)(1.0 / (1.0 + exp(-z)));
  }
}

extern "C" void kernel_launch(void* const* d_in, const int* in_sizes, int n_in,
                              void* d_out, int out_size, void* d_ws, size_t ws_size,
                              hipStream_t stream) {
  const float* x  = (const float*)d_in[0];
  const float* W1 = (const float*)d_in[1];
  const float* b1 = (const float*)d_in[2];
  const float* W2 = (const float*)d_in[3];
  const float* b2 = (const float*)d_in[4];
  const float* W3 = (const float*)d_in[5];
  const float* b3 = (const float*)d_in[6];
  float* out = (float*)d_out;

  // Per-sample workspace: masks 25*32*4 = 3200 B, cur2 25*512*4 = 51200 B.
  const long long per_sample = 54400;
  long long smax = (d_ws != nullptr) ? (long long)(ws_size / per_sample) : 0;
  long long scap = smax > 65536 ? 65536 : smax;
  int S = (int)(scap & ~63LL);

  if (S >= 256) {
    u32* masks = (u32*)d_ws;
    float* cur2 = (float*)((char*)d_ws + (size_t)S * 3200);
    for (int s0 = 0; s0 < 65536; s0 += S) {
      int Sc = (65536 - s0 < S) ? (65536 - s0) : S;
      hipLaunchKernelGGL(k_spk1, dim3(Sc / 4), dim3(256), 0, stream,
                         x, W1, b1, masks, s0, Sc);
      hipLaunchKernelGGL(k_cur2, dim3(((Sc / 16) * 25) / 4), dim3(256), 0, stream,
                         W2, b2, masks, cur2, Sc);
      hipLaunchKernelGGL(k_tail, dim3(Sc / 4), dim3(256), 0, stream,
                         cur2, W3, b3, out, s0, Sc);
    }
  } else {
    hipLaunchKernelGGL(k_snn, dim3(16384), dim3(256), 0, stream,
                       x, W1, b1, W2, b2, W3, b3, out);
  }
}